// Round 22
// baseline (145.156 us; speedup 1.0000x reference)
//
#include <hip/hip_runtime.h>
#include <hip/hip_bf16.h>

#define D 64
#define ED 32
#define NN 50000
#define EE 800000
#define NT64 (EE / 64)   // 12500 64-edge tiles, exact
#define NWN (NN / 16)    // 3125 16-node tiles, exact

#define PREP_N (4 * D * D + D * ED)          // 18432 prep elements
#define NB_PREP ((PREP_N + 255) / 256)       // 72
#define NB_NODE ((NWN + 3) / 4)              // 782
#define NB_SCAN ((NN + 255) / 256)           // 196
#define B_RANK 125                           // 800000/125 = 6400 (16B-aligned slabs)
#define EPB (EE / B_RANK)                    // 6400 edges per rank-block
#define NI4 (EPB / 4)                        // 1600 int4s per block
#define NPHASE 4
#define NPH 12800                            // nodes per LDS phase (4*12800 >= 50000)
#define LDSW (NPH / 2)                       // 6400 packed u16-pair counters (25.6 KB)

typedef __attribute__((ext_vector_type(8))) short bf16x8;
typedef __attribute__((ext_vector_type(4))) float f32x4;
typedef __attribute__((ext_vector_type(4))) unsigned uint4v;
typedef __attribute__((ext_vector_type(4))) int int4v;
typedef __attribute__((ext_vector_type(4))) unsigned short us4v;

__device__ __forceinline__ short f2bf(float f) {
    __hip_bfloat16 h = __float2bfloat16(f);
    return *reinterpret_cast<short*>(&h);
}
__device__ __forceinline__ float bfhi2f(unsigned w) { return __uint_as_float(w & 0xFFFF0000u); }
__device__ __forceinline__ float bflo2f(unsigned w) { return __uint_as_float(w << 16); }
__device__ __forceinline__ float us2f(unsigned short u) { return __uint_as_float(((unsigned)u) << 16); }
__device__ __forceinline__ unsigned packqv(float q, float v) {
    return (unsigned)(unsigned short)f2bf(q) | ((unsigned)(unsigned short)f2bf(v) << 16);
}

// Weight prep (WnT natural layout; WgT/WvT column-permuted) + gctr zero.
__global__ void prep_w(const float* __restrict__ Wk, const float* __restrict__ Wq,
                       const float* __restrict__ Wv, const float* __restrict__ Ws,
                       unsigned short* __restrict__ WnT,
                       unsigned short* __restrict__ WgT, unsigned short* __restrict__ WvT,
                       int* __restrict__ gctr) {
    if (blockIdx.x == 0 && threadIdx.x == 0) *gctr = 0;
    const int i = blockIdx.x * 256 + threadIdx.x;
    if (i < 4 * D * D) {
        const int m = i >> 12, col = (i >> 6) & 63, k = i & 63;
        const float* W = (m == 0) ? Ws : (m == 1) ? Wk : (m == 2) ? Wq : Wv;
        WnT[i] = (unsigned short)f2bf(W[k * D + col]);
    } else if (i < PREP_N) {
        const int j = i - 4 * D * D;
        const int c = j >> 5, k = j & 31;
        const int cp = 4 * (c & 15) + (c >> 4);     // permuted column
        const size_t off = (size_t)(D + k) * D + cp;
        WgT[j] = (unsigned short)f2bf(Wk[off] + Wq[off]);
        WvT[j] = (unsigned short)f2bf(Wv[off]);
    }
}

// MERGED: LDS-local ranking (blocks 0..124) + MFMA node transforms (125..906).
// r22 change: 4 phases x 12800 nodes -> LDS 25.6 KB (was 50), launch_bounds
// (256,5) -> 5 blocks/CU residency for the node half (was 3). Phase re-scans
// read the register-cached dstI slab, so extra phases are nearly free.
__global__ __launch_bounds__(256, 5)
void rank_node(const int* __restrict__ dstI,
               unsigned short* __restrict__ lrank, unsigned short* __restrict__ H,
               const float* __restrict__ x, const unsigned short* __restrict__ WnT,
               const float* __restrict__ bk, const float* __restrict__ bq,
               const float* __restrict__ bv, const float* __restrict__ bias,
               unsigned short* __restrict__ kb, unsigned* __restrict__ qv,
               float* __restrict__ out) {
    __shared__ unsigned cnt[LDSW];   // 25.6 KB
    const int blk = blockIdx.x;
    if (blk < B_RANK) {
        const int e0 = blk * EPB;
        int4v dv[7];
        unsigned short lr4[7][4];
#pragma unroll
        for (int k = 0; k < 7; ++k) {
            const int i4 = threadIdx.x + 256 * k;
            dv[k] = (i4 < NI4)
                ? __builtin_nontemporal_load((const int4v*)(dstI + e0 + 4 * i4))
                : (int4v){-1, -1, -1, -1};
        }
#pragma unroll 1
        for (int ph = 0; ph < NPHASE; ++ph) {
            const int base = ph * NPH;
            for (int j4 = threadIdx.x; j4 < LDSW / 4; j4 += 256)
                ((uint4v*)cnt)[j4] = (uint4v){0, 0, 0, 0};
            __syncthreads();
#pragma unroll
            for (int k = 0; k < 7; ++k) {
                const int i4 = threadIdx.x + 256 * k;
                if (i4 < NI4) {
#pragma unroll
                    for (int r = 0; r < 4; ++r) {
                        const unsigned dl = (unsigned)(dv[k][r] - base);
                        if (dl < (unsigned)NPH) {
                            const unsigned sh = (dl & 1u) * 16u;
                            const unsigned old = atomicAdd(&cnt[dl >> 1], 1u << sh);
                            lr4[k][r] = (unsigned short)((old >> sh) & 0xFFFFu);
                        }
                    }
                }
            }
            __syncthreads();
            // dump only the nodes this phase covers (last phase is partial)
            const int rem = NN - base;
            const int w32 = ((rem < NPH) ? rem : NPH) / 2;   // u32 words
            unsigned* H32 = (unsigned*)(H + (size_t)blk * NN + base);
            for (int j4 = threadIdx.x; j4 < w32 / 4; j4 += 256)
                ((uint4v*)H32)[j4] = ((uint4v*)cnt)[j4];
            __syncthreads();
        }
#pragma unroll
        for (int k = 0; k < 7; ++k) {
            const int i4 = threadIdx.x + 256 * k;
            if (i4 < NI4) {
                const us4v v = {lr4[k][0], lr4[k][1], lr4[k][2], lr4[k][3]};
                __builtin_nontemporal_store(v, (us4v*)(lrank + e0 + 4 * i4));
            }
        }
        return;
    }
    // ---- node transforms: 16 nodes per wave ----
    const int lane = threadIdx.x & 63;
    const int wid  = (blk - B_RANK) * 4 + (threadIdx.x >> 6);
    if (wid >= NWN) return;
    const int lg = lane >> 4, lr = lane & 15;
    const int n0 = wid * 16;

    const float* xp = x + (size_t)(n0 + lr) * D + 8 * lg;
    const f32x4 x00 = *(const f32x4*)xp;
    const f32x4 x01 = *(const f32x4*)(xp + 4);
    const f32x4 x10 = *(const f32x4*)(xp + 32);
    const f32x4 x11 = *(const f32x4*)(xp + 36);
    bf16x8 af0, af1;
#pragma unroll
    for (int e = 0; e < 4; ++e) {
        af0[e] = f2bf(x00[e]); af0[e + 4] = f2bf(x01[e]);
        af1[e] = f2bf(x10[e]); af1[e + 4] = f2bf(x11[e]);
    }

    f32x4 acc[4], accQ[4];
#pragma unroll
    for (int m = 0; m < 4; ++m) {
        f32x4* A = (m == 2) ? accQ : acc;
#pragma unroll
        for (int h = 0; h < 4; ++h) {
            const bf16x8 b0 = *(const bf16x8*)(WnT + (size_t)(m * D + 16 * h + lr) * D + 8 * lg);
            const bf16x8 b1 = *(const bf16x8*)(WnT + (size_t)(m * D + 16 * h + lr) * D + 32 + 8 * lg);
            A[h] = __builtin_amdgcn_mfma_f32_16x16x32_bf16(af0, b0, (f32x4)(0.f), 0, 0, 0);
            A[h] = __builtin_amdgcn_mfma_f32_16x16x32_bf16(af1, b1, A[h], 0, 0, 0);
        }
        if (m == 0) {
#pragma unroll
            for (int r = 0; r < 4; ++r)
#pragma unroll
                for (int h = 0; h < 4; ++h)
                    out[(size_t)(n0 + 4 * lg + r) * D + 16 * h + lr] = acc[h][r] + bias[16 * h + lr];
        } else if (m == 1) {
#pragma unroll
            for (int r = 0; r < 4; ++r)
#pragma unroll
                for (int h = 0; h < 4; ++h)
                    kb[(size_t)(n0 + 4 * lg + r) * D + 16 * h + lr] =
                        (unsigned short)f2bf(acc[h][r] + bk[16 * h + lr]);
        } else if (m == 3) {
#pragma unroll
            for (int r = 0; r < 4; ++r)
#pragma unroll
                for (int h = 0; h < 4; ++h)
                    qv[(size_t)(n0 + 4 * lg + r) * D + 16 * h + lr] =
                        packqv(accQ[h][r] + bq[16 * h + lr], acc[h][r] + bv[16 * h + lr]);
        }
    }
}

// Column scan over 125 block-histograms (in place H -> cross-block prefix P)
// fused with block scan + atomic global base -> off[d].
__global__ __launch_bounds__(256)
void k_colscanA(unsigned short* __restrict__ H, int* __restrict__ off,
                int* __restrict__ gctr) {
    __shared__ int s_tmp[256];
    __shared__ int s_base;
    const int t = threadIdx.x, d = blockIdx.x * 256 + t;
    int acc = 0;
    if (d < NN) {
#pragma unroll 5
        for (int b = 0; b < B_RANK; ++b) {
            const int idx = b * NN + d;          // coalesced across threads
            const unsigned short h = H[idx];
            H[idx] = (unsigned short)acc;        // in-place P[b][d]
            acc += h;
        }
    }
    s_tmp[t] = acc;
    __syncthreads();
    for (int dd = 1; dd < 256; dd <<= 1) {
        const int add = (t >= dd) ? s_tmp[t - dd] : 0;
        __syncthreads();
        s_tmp[t] += add;
        __syncthreads();
    }
    if (t == 255) s_base = atomicAdd(gctr, s_tmp[255]);
    __syncthreads();
    if (d < NN) off[d] = s_base + s_tmp[t] - acc;
}

// Atomic-free scatter: p = off[d] + P[e/EPB][d] + lrank[e].
__global__ void k_scatter(const int* __restrict__ srcI, const int* __restrict__ dstI,
                          const unsigned short* __restrict__ lrank,
                          const unsigned short* __restrict__ P,
                          const int* __restrict__ off,
                          unsigned long long* __restrict__ rec) {
    const int e = blockIdx.x * 256 + threadIdx.x;
    const int s = srcI[e], d = dstI[e];
    const int b = e / EPB;
    const int p = off[d] + (int)P[b * NN + d] + (int)lrank[e];
    __builtin_nontemporal_store(
        ((unsigned long long)(unsigned)e << 32) | (unsigned)(s | (d << 16)),
        rec + p);
}

// Edge-parallel aggregation (FROZEN, single dispatch).
__global__ __launch_bounds__(256, 4)
void agg_sorted(const unsigned* __restrict__ rec, const float* __restrict__ ea,
                const unsigned short* __restrict__ WgT, const unsigned short* __restrict__ WvT,
                const unsigned short* __restrict__ kb, const unsigned* __restrict__ qv,
                float* __restrict__ out) {
    const int lane = threadIdx.x & 63;
    const int wid  = blockIdx.x * 4 + (threadIdx.x >> 6);   // tile id, grid exact
    const int lg = lane >> 4;
    const int lr = lane & 15;
    const int e0 = wid * 64;

    bf16x8 bg[4], bvf[4];
#pragma unroll
    for (int h = 0; h < 4; ++h) {
        bg[h]  = *(const bf16x8*)(WgT + (size_t)(16 * h + lr) * ED + 8 * lg);
        bvf[h] = *(const bf16x8*)(WvT + (size_t)(16 * h + lr) * ED + 8 * lg);
    }

#pragma unroll
    for (int g = 0; g < 4; ++g) {
        const int gb = e0 + 16 * g;
        const uint4v rA = *(const uint4v*)(rec + 2 * (gb + 4 * lg));
        const uint4v rB = *(const uint4v*)(rec + 2 * (gb + 4 * lg) + 4);
        int dR[4], sR[4];
        dR[0] = (int)(rA.x >> 16); sR[0] = (int)(rA.x & 0xFFFFu);
        dR[1] = (int)(rA.z >> 16); sR[1] = (int)(rA.z & 0xFFFFu);
        dR[2] = (int)(rB.x >> 16); sR[2] = (int)(rB.x & 0xFFFFu);
        dR[3] = (int)(rB.z >> 16); sR[3] = (int)(rB.z & 0xFFFFu);

        const unsigned pl = rec[2 * (gb + lr) + 1];
        const float* ap = ea + (size_t)pl * ED + 8 * lg;
        const f32x4 a0 = __builtin_nontemporal_load((const f32x4*)ap);
        const f32x4 a1 = __builtin_nontemporal_load((const f32x4*)(ap + 4));

        // vector gathers: per C-row one uint4 (qv, 16B) + one ushort4 (kb, 8B)
        uint4v qd[4];
        us4v   kd[4];
#pragma unroll
        for (int r = 0; r < 4; ++r) {
            qd[r] = *(const uint4v*)(qv + (size_t)sR[r] * D + 4 * lr);
            kd[r] = *(const us4v*)(kb + (size_t)dR[r] * D + 4 * lr);
        }

        bf16x8 af;
#pragma unroll
        for (int e2 = 0; e2 < 4; ++e2) { af[e2] = f2bf(a0[e2]); af[e2 + 4] = f2bf(a1[e2]); }

        f32x4 accG[4], accV[4];
#pragma unroll
        for (int h = 0; h < 4; ++h) {
            accG[h] = __builtin_amdgcn_mfma_f32_16x16x32_bf16(af, bg[h],  (f32x4)(0.f), 0, 0, 0);
            accV[h] = __builtin_amdgcn_mfma_f32_16x16x32_bf16(af, bvf[h], (f32x4)(0.f), 0, 0, 0);
        }

        // msg[r][h]: edge gb+4lg+r, logical dim 4lr+h
        float msg[4][4];
#pragma unroll
        for (int r = 0; r < 4; ++r)
#pragma unroll
            for (int h = 0; h < 4; ++h) {
                const float z = accG[h][r] + us2f(kd[r][h]) + bflo2f(qd[r][h]);
                const float v = accV[h][r] + bfhi2f(qd[r][h]);
                msg[r][h] = v * __builtin_amdgcn_rcpf(1.0f + __expf(-z));
            }

        bool done[4] = {false, false, false, false};
        while (true) {
            int m0 = 0x7FFFFFFF;
#pragma unroll
            for (int r = 0; r < 4; ++r) m0 = min(m0, done[r] ? 0x7FFFFFFF : dR[r]);
            m0 = min(m0, __shfl_xor(m0, 16, 64));
            m0 = min(m0, __shfl_xor(m0, 32, 64));
            if (m0 == 0x7FFFFFFF) break;          // wave-uniform exit
            float sh[4];
#pragma unroll
            for (int h = 0; h < 4; ++h) {
                float a = 0.f;
#pragma unroll
                for (int r = 0; r < 4; ++r) a += (dR[r] == m0) ? msg[r][h] : 0.f;
                a += __shfl_xor(a, 16, 64);
                a += __shfl_xor(a, 32, 64);
                sh[h] = a;        // every lane: run-total for dim 4*(lane&15)+h
            }
#pragma unroll
            for (int r = 0; r < 4; ++r) done[r] = done[r] || (dR[r] == m0);
            // transpose: lane j takes dim j = 4*(j>>2) + (j&3)
            const int qsrc = lane >> 2;
            const float t0 = __shfl(sh[0], qsrc, 64);
            const float t1 = __shfl(sh[1], qsrc, 64);
            const float t2 = __shfl(sh[2], qsrc, 64);
            const float t3 = __shfl(sh[3], qsrc, 64);
            const int hs = lane & 3;
            const float val = (hs == 0) ? t0 : (hs == 1) ? t1 : (hs == 2) ? t2 : t3;
            // one contiguous 256B wave-atomic per run
            unsafeAtomicAdd(&out[(size_t)m0 * D + lane], val);
        }
    }
}

extern "C" void kernel_launch(void* const* d_in, const int* in_sizes, int n_in,
                              void* d_out, int out_size, void* d_ws, size_t ws_size,
                              hipStream_t stream) {
    const float* x    = (const float*)d_in[0];
    const int*   eidx = (const int*)d_in[1];      // [2, E]: row0=src, row1=dst
    const float* eatt = (const float*)d_in[2];
    const float* Wk   = (const float*)d_in[3];
    const float* bk   = (const float*)d_in[4];
    const float* Wq   = (const float*)d_in[5];
    const float* bq   = (const float*)d_in[6];
    const float* Wv   = (const float*)d_in[7];
    const float* bv   = (const float*)d_in[8];
    const float* Ws   = (const float*)d_in[9];
    const float* bias = (const float*)d_in[10];
    float* out = (float*)d_out;

    // workspace carve (offsets keep 16B alignment); total ~40 MB
    char* w = (char*)d_ws;
    unsigned short* kb = (unsigned short*)w;   w += (size_t)NN * D * 2;  // 6.4 MB
    unsigned* qv  = (unsigned*)w;              w += (size_t)NN * D * 4;  // 12.8 MB
    unsigned short* WnT = (unsigned short*)w;  w += 4 * D * D * 2;       // 32 KB
    unsigned short* WgT = (unsigned short*)w;  w += D * ED * 2;          // 4 KB
    unsigned short* WvT = (unsigned short*)w;  w += D * ED * 2;          // 4 KB
    int* gctr = (int*)w;                       w += 16;                  // 16 B
    int* off  = (int*)w;                       w += (size_t)NN * 4;      // 200 KB
    unsigned short* lrank = (unsigned short*)w; w += (size_t)EE * 2;     // 1.6 MB
    unsigned short* H = (unsigned short*)w;    w += (size_t)B_RANK * NN * 2; // 12.5 MB
    unsigned long long* rec = (unsigned long long*)w;                    // 6.4 MB

    const int* srcI = eidx;
    const int* dstI = eidx + EE;

    // 1) weight prep + gctr zero
    prep_w<<<NB_PREP, 256, 0, stream>>>(Wk, Wq, Wv, Ws, WnT, WgT, WvT, gctr);
    // 2) MERGED rank (125 blocks, 4-phase 25.6KB LDS) + node transforms
    rank_node<<<B_RANK + NB_NODE, 256, 0, stream>>>(dstI, lrank, H,
                                                    x, WnT, bk, bq, bv, bias,
                                                    kb, qv, out);
    // 3) column scan (H -> P in place) + block scan + atomic base -> off
    k_colscanA<<<NB_SCAN, 256, 0, stream>>>(H, off, gctr);
    // 4) atomic-free scatter into dst-grouped records
    k_scatter<<<EE / 256, 256, 0, stream>>>(srcI, dstI, lrank, H, off, rec);
    // 5) aggregation (single dispatch)
    agg_sorted<<<NT64 / 4, 256, 0, stream>>>((const unsigned*)rec, eatt,
                                             WgT, WvT, kb, qv, out);
}

// Round 23
// 131.582 us; speedup vs baseline: 1.1032x; 1.1032x over previous
//
#include <hip/hip_runtime.h>
#include <hip/hip_bf16.h>

#define D 64
#define ED 32
#define NN 50000
#define EE 800000
#define NT64 (EE / 64)   // 12500 64-edge tiles, exact
#define NWN (NN / 16)    // 3125 16-node tiles, exact

#define PREP_N (4 * D * D + D * ED)          // 18432 prep elements
#define NB_PREP ((PREP_N + 255) / 256)       // 72
#define NB_NODE ((NWN + 3) / 4)              // 782
#define NB_SCAN ((NN + 255) / 256)           // 196
#define B_RANK 125                           // 800000/125 = 6400 (16B-aligned slabs)
#define EPB (EE / B_RANK)                    // 6400 edges per rank-block
#define NI4 (EPB / 4)                        // 1600 int4s per block
#define NPH 25000                            // nodes per LDS phase
#define LDSW (NPH / 2)                       // 12500 packed u16-pair counters

typedef __attribute__((ext_vector_type(8))) short bf16x8;
typedef __attribute__((ext_vector_type(4))) float f32x4;
typedef __attribute__((ext_vector_type(4))) unsigned uint4v;
typedef __attribute__((ext_vector_type(4))) int int4v;
typedef __attribute__((ext_vector_type(4))) unsigned short us4v;

__device__ __forceinline__ short f2bf(float f) {
    __hip_bfloat16 h = __float2bfloat16(f);
    return *reinterpret_cast<short*>(&h);
}
__device__ __forceinline__ float bfhi2f(unsigned w) { return __uint_as_float(w & 0xFFFF0000u); }
__device__ __forceinline__ float bflo2f(unsigned w) { return __uint_as_float(w << 16); }
__device__ __forceinline__ float us2f(unsigned short u) { return __uint_as_float(((unsigned)u) << 16); }
__device__ __forceinline__ unsigned packqv(float q, float v) {
    return (unsigned)(unsigned short)f2bf(q) | ((unsigned)(unsigned short)f2bf(v) << 16);
}

// Weight prep (WnT natural layout; WgT/WvT column-permuted) + gctr zero.
__global__ void prep_w(const float* __restrict__ Wk, const float* __restrict__ Wq,
                       const float* __restrict__ Wv, const float* __restrict__ Ws,
                       unsigned short* __restrict__ WnT,
                       unsigned short* __restrict__ WgT, unsigned short* __restrict__ WvT,
                       int* __restrict__ gctr) {
    if (blockIdx.x == 0 && threadIdx.x == 0) *gctr = 0;
    const int i = blockIdx.x * 256 + threadIdx.x;
    if (i < 4 * D * D) {
        const int m = i >> 12, col = (i >> 6) & 63, k = i & 63;
        const float* W = (m == 0) ? Ws : (m == 1) ? Wk : (m == 2) ? Wq : Wv;
        WnT[i] = (unsigned short)f2bf(W[k * D + col]);
    } else if (i < PREP_N) {
        const int j = i - 4 * D * D;
        const int c = j >> 5, k = j & 31;
        const int cp = 4 * (c & 15) + (c >> 4);     // permuted column
        const size_t off = (size_t)(D + k) * D + cp;
        WgT[j] = (unsigned short)f2bf(Wk[off] + Wq[off]);
        WvT[j] = (unsigned short)f2bf(Wv[off]);
    }
}

// MERGED: LDS-local ranking (blocks 0..124, vectorized: register-cached dstI
// slab, uint4 zero/dump, coalesced us4 lrank stores) + MFMA node transforms.
// r21 config (2 phases x 25k nodes, 50KB LDS, 3 blk/CU) — validated best;
// r22's 4-phase shrink regressed (+13us barrier overhead in the rank half).
__global__ __launch_bounds__(256, 3)
void rank_node(const int* __restrict__ dstI,
               unsigned short* __restrict__ lrank, unsigned short* __restrict__ H,
               const float* __restrict__ x, const unsigned short* __restrict__ WnT,
               const float* __restrict__ bk, const float* __restrict__ bq,
               const float* __restrict__ bv, const float* __restrict__ bias,
               unsigned short* __restrict__ kb, unsigned* __restrict__ qv,
               float* __restrict__ out) {
    __shared__ unsigned cnt[LDSW];   // 50 KB (rank blocks only; caps 3 blk/CU)
    const int blk = blockIdx.x;
    if (blk < B_RANK) {
        const int e0 = blk * EPB;
        int4v dv[7];
        unsigned short lr4[7][4];
#pragma unroll
        for (int k = 0; k < 7; ++k) {
            const int i4 = threadIdx.x + 256 * k;
            dv[k] = (i4 < NI4)
                ? __builtin_nontemporal_load((const int4v*)(dstI + e0 + 4 * i4))
                : (int4v){-1, -1, -1, -1};
        }
#pragma unroll 1
        for (int ph = 0; ph < 2; ++ph) {
            const int base = ph * NPH;
            for (int j4 = threadIdx.x; j4 < LDSW / 4; j4 += 256)
                ((uint4v*)cnt)[j4] = (uint4v){0, 0, 0, 0};
            __syncthreads();
#pragma unroll
            for (int k = 0; k < 7; ++k) {
                const int i4 = threadIdx.x + 256 * k;
                if (i4 < NI4) {
#pragma unroll
                    for (int r = 0; r < 4; ++r) {
                        const unsigned dl = (unsigned)(dv[k][r] - base);
                        if (dl < (unsigned)NPH) {
                            const unsigned sh = (dl & 1u) * 16u;
                            const unsigned old = atomicAdd(&cnt[dl >> 1], 1u << sh);
                            lr4[k][r] = (unsigned short)((old >> sh) & 0xFFFFu);
                        }
                    }
                }
            }
            __syncthreads();
            unsigned* H32 = (unsigned*)(H + (size_t)blk * NN + base);
            for (int j4 = threadIdx.x; j4 < LDSW / 4; j4 += 256)
                ((uint4v*)H32)[j4] = ((uint4v*)cnt)[j4];
            __syncthreads();
        }
#pragma unroll
        for (int k = 0; k < 7; ++k) {
            const int i4 = threadIdx.x + 256 * k;
            if (i4 < NI4) {
                const us4v v = {lr4[k][0], lr4[k][1], lr4[k][2], lr4[k][3]};
                __builtin_nontemporal_store(v, (us4v*)(lrank + e0 + 4 * i4));
            }
        }
        return;
    }
    // ---- node transforms: 16 nodes per wave ----
    const int lane = threadIdx.x & 63;
    const int wid  = (blk - B_RANK) * 4 + (threadIdx.x >> 6);
    if (wid >= NWN) return;
    const int lg = lane >> 4, lr = lane & 15;
    const int n0 = wid * 16;

    const float* xp = x + (size_t)(n0 + lr) * D + 8 * lg;
    const f32x4 x00 = *(const f32x4*)xp;
    const f32x4 x01 = *(const f32x4*)(xp + 4);
    const f32x4 x10 = *(const f32x4*)(xp + 32);
    const f32x4 x11 = *(const f32x4*)(xp + 36);
    bf16x8 af0, af1;
#pragma unroll
    for (int e = 0; e < 4; ++e) {
        af0[e] = f2bf(x00[e]); af0[e + 4] = f2bf(x01[e]);
        af1[e] = f2bf(x10[e]); af1[e + 4] = f2bf(x11[e]);
    }

    f32x4 acc[4], accQ[4];
#pragma unroll
    for (int m = 0; m < 4; ++m) {
        f32x4* A = (m == 2) ? accQ : acc;
#pragma unroll
        for (int h = 0; h < 4; ++h) {
            const bf16x8 b0 = *(const bf16x8*)(WnT + (size_t)(m * D + 16 * h + lr) * D + 8 * lg);
            const bf16x8 b1 = *(const bf16x8*)(WnT + (size_t)(m * D + 16 * h + lr) * D + 32 + 8 * lg);
            A[h] = __builtin_amdgcn_mfma_f32_16x16x32_bf16(af0, b0, (f32x4)(0.f), 0, 0, 0);
            A[h] = __builtin_amdgcn_mfma_f32_16x16x32_bf16(af1, b1, A[h], 0, 0, 0);
        }
        if (m == 0) {
#pragma unroll
            for (int r = 0; r < 4; ++r)
#pragma unroll
                for (int h = 0; h < 4; ++h)
                    out[(size_t)(n0 + 4 * lg + r) * D + 16 * h + lr] = acc[h][r] + bias[16 * h + lr];
        } else if (m == 1) {
#pragma unroll
            for (int r = 0; r < 4; ++r)
#pragma unroll
                for (int h = 0; h < 4; ++h)
                    kb[(size_t)(n0 + 4 * lg + r) * D + 16 * h + lr] =
                        (unsigned short)f2bf(acc[h][r] + bk[16 * h + lr]);
        } else if (m == 3) {
#pragma unroll
            for (int r = 0; r < 4; ++r)
#pragma unroll
                for (int h = 0; h < 4; ++h)
                    qv[(size_t)(n0 + 4 * lg + r) * D + 16 * h + lr] =
                        packqv(accQ[h][r] + bq[16 * h + lr], acc[h][r] + bv[16 * h + lr]);
        }
    }
}

// Column scan over 125 block-histograms (in place H -> cross-block prefix P)
// fused with block scan + atomic global base -> off[d].
__global__ __launch_bounds__(256)
void k_colscanA(unsigned short* __restrict__ H, int* __restrict__ off,
                int* __restrict__ gctr) {
    __shared__ int s_tmp[256];
    __shared__ int s_base;
    const int t = threadIdx.x, d = blockIdx.x * 256 + t;
    int acc = 0;
    if (d < NN) {
#pragma unroll 5
        for (int b = 0; b < B_RANK; ++b) {
            const int idx = b * NN + d;          // coalesced across threads
            const unsigned short h = H[idx];
            H[idx] = (unsigned short)acc;        // in-place P[b][d]
            acc += h;
        }
    }
    s_tmp[t] = acc;
    __syncthreads();
    for (int dd = 1; dd < 256; dd <<= 1) {
        const int add = (t >= dd) ? s_tmp[t - dd] : 0;
        __syncthreads();
        s_tmp[t] += add;
        __syncthreads();
    }
    if (t == 255) s_base = atomicAdd(gctr, s_tmp[255]);
    __syncthreads();
    if (d < NN) off[d] = s_base + s_tmp[t] - acc;
}

// Atomic-free scatter: p = off[d] + P[e/EPB][d] + lrank[e].
__global__ void k_scatter(const int* __restrict__ srcI, const int* __restrict__ dstI,
                          const unsigned short* __restrict__ lrank,
                          const unsigned short* __restrict__ P,
                          const int* __restrict__ off,
                          unsigned long long* __restrict__ rec) {
    const int e = blockIdx.x * 256 + threadIdx.x;
    const int s = srcI[e], d = dstI[e];
    const int b = e / EPB;
    const int p = off[d] + (int)P[b * NN + d] + (int)lrank[e];
    __builtin_nontemporal_store(
        ((unsigned long long)(unsigned)e << 32) | (unsigned)(s | (d << 16)),
        rec + p);
}

// Edge-parallel aggregation (FROZEN, single dispatch — proven fastest config).
__global__ __launch_bounds__(256, 4)
void agg_sorted(const unsigned* __restrict__ rec, const float* __restrict__ ea,
                const unsigned short* __restrict__ WgT, const unsigned short* __restrict__ WvT,
                const unsigned short* __restrict__ kb, const unsigned* __restrict__ qv,
                float* __restrict__ out) {
    const int lane = threadIdx.x & 63;
    const int wid  = blockIdx.x * 4 + (threadIdx.x >> 6);   // tile id, grid exact
    const int lg = lane >> 4;
    const int lr = lane & 15;
    const int e0 = wid * 64;

    bf16x8 bg[4], bvf[4];
#pragma unroll
    for (int h = 0; h < 4; ++h) {
        bg[h]  = *(const bf16x8*)(WgT + (size_t)(16 * h + lr) * ED + 8 * lg);
        bvf[h] = *(const bf16x8*)(WvT + (size_t)(16 * h + lr) * ED + 8 * lg);
    }

#pragma unroll
    for (int g = 0; g < 4; ++g) {
        const int gb = e0 + 16 * g;
        const uint4v rA = *(const uint4v*)(rec + 2 * (gb + 4 * lg));
        const uint4v rB = *(const uint4v*)(rec + 2 * (gb + 4 * lg) + 4);
        int dR[4], sR[4];
        dR[0] = (int)(rA.x >> 16); sR[0] = (int)(rA.x & 0xFFFFu);
        dR[1] = (int)(rA.z >> 16); sR[1] = (int)(rA.z & 0xFFFFu);
        dR[2] = (int)(rB.x >> 16); sR[2] = (int)(rB.x & 0xFFFFu);
        dR[3] = (int)(rB.z >> 16); sR[3] = (int)(rB.z & 0xFFFFu);

        const unsigned pl = rec[2 * (gb + lr) + 1];
        const float* ap = ea + (size_t)pl * ED + 8 * lg;
        const f32x4 a0 = __builtin_nontemporal_load((const f32x4*)ap);
        const f32x4 a1 = __builtin_nontemporal_load((const f32x4*)(ap + 4));

        // vector gathers: per C-row one uint4 (qv, 16B) + one ushort4 (kb, 8B)
        uint4v qd[4];
        us4v   kd[4];
#pragma unroll
        for (int r = 0; r < 4; ++r) {
            qd[r] = *(const uint4v*)(qv + (size_t)sR[r] * D + 4 * lr);
            kd[r] = *(const us4v*)(kb + (size_t)dR[r] * D + 4 * lr);
        }

        bf16x8 af;
#pragma unroll
        for (int e2 = 0; e2 < 4; ++e2) { af[e2] = f2bf(a0[e2]); af[e2 + 4] = f2bf(a1[e2]); }

        f32x4 accG[4], accV[4];
#pragma unroll
        for (int h = 0; h < 4; ++h) {
            accG[h] = __builtin_amdgcn_mfma_f32_16x16x32_bf16(af, bg[h],  (f32x4)(0.f), 0, 0, 0);
            accV[h] = __builtin_amdgcn_mfma_f32_16x16x32_bf16(af, bvf[h], (f32x4)(0.f), 0, 0, 0);
        }

        // msg[r][h]: edge gb+4lg+r, logical dim 4lr+h
        float msg[4][4];
#pragma unroll
        for (int r = 0; r < 4; ++r)
#pragma unroll
            for (int h = 0; h < 4; ++h) {
                const float z = accG[h][r] + us2f(kd[r][h]) + bflo2f(qd[r][h]);
                const float v = accV[h][r] + bfhi2f(qd[r][h]);
                msg[r][h] = v * __builtin_amdgcn_rcpf(1.0f + __expf(-z));
            }

        bool done[4] = {false, false, false, false};
        while (true) {
            int m0 = 0x7FFFFFFF;
#pragma unroll
            for (int r = 0; r < 4; ++r) m0 = min(m0, done[r] ? 0x7FFFFFFF : dR[r]);
            m0 = min(m0, __shfl_xor(m0, 16, 64));
            m0 = min(m0, __shfl_xor(m0, 32, 64));
            if (m0 == 0x7FFFFFFF) break;          // wave-uniform exit
            float sh[4];
#pragma unroll
            for (int h = 0; h < 4; ++h) {
                float a = 0.f;
#pragma unroll
                for (int r = 0; r < 4; ++r) a += (dR[r] == m0) ? msg[r][h] : 0.f;
                a += __shfl_xor(a, 16, 64);
                a += __shfl_xor(a, 32, 64);
                sh[h] = a;        // every lane: run-total for dim 4*(lane&15)+h
            }
#pragma unroll
            for (int r = 0; r < 4; ++r) done[r] = done[r] || (dR[r] == m0);
            // transpose: lane j takes dim j = 4*(j>>2) + (j&3)
            const int qsrc = lane >> 2;
            const float t0 = __shfl(sh[0], qsrc, 64);
            const float t1 = __shfl(sh[1], qsrc, 64);
            const float t2 = __shfl(sh[2], qsrc, 64);
            const float t3 = __shfl(sh[3], qsrc, 64);
            const int hs = lane & 3;
            const float val = (hs == 0) ? t0 : (hs == 1) ? t1 : (hs == 2) ? t2 : t3;
            // one contiguous 256B wave-atomic per run
            unsafeAtomicAdd(&out[(size_t)m0 * D + lane], val);
        }
    }
}

extern "C" void kernel_launch(void* const* d_in, const int* in_sizes, int n_in,
                              void* d_out, int out_size, void* d_ws, size_t ws_size,
                              hipStream_t stream) {
    const float* x    = (const float*)d_in[0];
    const int*   eidx = (const int*)d_in[1];      // [2, E]: row0=src, row1=dst
    const float* eatt = (const float*)d_in[2];
    const float* Wk   = (const float*)d_in[3];
    const float* bk   = (const float*)d_in[4];
    const float* Wq   = (const float*)d_in[5];
    const float* bq   = (const float*)d_in[6];
    const float* Wv   = (const float*)d_in[7];
    const float* bv   = (const float*)d_in[8];
    const float* Ws   = (const float*)d_in[9];
    const float* bias = (const float*)d_in[10];
    float* out = (float*)d_out;

    // workspace carve (offsets keep 16B alignment); total ~40 MB
    char* w = (char*)d_ws;
    unsigned short* kb = (unsigned short*)w;   w += (size_t)NN * D * 2;  // 6.4 MB
    unsigned* qv  = (unsigned*)w;              w += (size_t)NN * D * 4;  // 12.8 MB
    unsigned short* WnT = (unsigned short*)w;  w += 4 * D * D * 2;       // 32 KB
    unsigned short* WgT = (unsigned short*)w;  w += D * ED * 2;          // 4 KB
    unsigned short* WvT = (unsigned short*)w;  w += D * ED * 2;          // 4 KB
    int* gctr = (int*)w;                       w += 16;                  // 16 B
    int* off  = (int*)w;                       w += (size_t)NN * 4;      // 200 KB
    unsigned short* lrank = (unsigned short*)w; w += (size_t)EE * 2;     // 1.6 MB
    unsigned short* H = (unsigned short*)w;    w += (size_t)B_RANK * NN * 2; // 12.5 MB
    unsigned long long* rec = (unsigned long long*)w;                    // 6.4 MB

    const int* srcI = eidx;
    const int* dstI = eidx + EE;

    // 1) weight prep + gctr zero
    prep_w<<<NB_PREP, 256, 0, stream>>>(Wk, Wq, Wv, Ws, WnT, WgT, WvT, gctr);
    // 2) MERGED rank (125 blocks, vectorized, 2-phase 50KB LDS) + node transforms
    rank_node<<<B_RANK + NB_NODE, 256, 0, stream>>>(dstI, lrank, H,
                                                    x, WnT, bk, bq, bv, bias,
                                                    kb, qv, out);
    // 3) column scan (H -> P in place) + block scan + atomic base -> off
    k_colscanA<<<NB_SCAN, 256, 0, stream>>>(H, off, gctr);
    // 4) atomic-free scatter into dst-grouped records
    k_scatter<<<EE / 256, 256, 0, stream>>>(srcI, dstI, lrank, H, off, rec);
    // 5) aggregation (single dispatch — proven fastest config)
    agg_sorted<<<NT64 / 4, 256, 0, stream>>>((const unsigned*)rec, eatt,
                                             WgT, WvT, kb, qv, out);
}